// Round 1
// baseline (746.464 us; speedup 1.0000x reference)
//
#include <hip/hip_runtime.h>
#include <cstdint>

#define BATCH   16
#define NCLS    80
#define NOUT    85      // 5 + NCLS
#define NANC    3
#define NCAND   25200   // 3*(6400+1600+400)
#define CONF    0.25f
#define IOUT    0.45f
#define TOPK    1000
#define MAXDET  300
#define MAXWH   4096.0f
#define NBUCK   65536
#define CAPK    2048

// ---------------- workspace layout (bytes) ----------------
constexpr size_t SCORE_OFF = 0;                                          // f32 [16][25200]
constexpr size_t CLS_OFF   = SCORE_OFF + (size_t)BATCH * NCAND * 4;      // i32 [16][25200]
constexpr size_t HIST_OFF  = CLS_OFF   + (size_t)BATCH * NCAND * 4;      // u32 [16][65536]
constexpr size_t THR_OFF   = HIST_OFF  + (size_t)BATCH * NBUCK * 4;      // u32 [16] (+pad)
constexpr size_t CNT_OFF   = THR_OFF   + 256;                            // u32 [16] (+pad)
constexpr size_t KEYS_OFF  = CNT_OFF   + 256;                            // u64 [16][2048]
constexpr size_t RS_OFF    = KEYS_OFF  + (size_t)BATCH * CAPK * 8;       // f32 [16][1000]
constexpr size_t RBOX_OFF  = RS_OFF    + (size_t)BATCH * TOPK * 4;       // f32 [16][1000][4]
constexpr size_t RBO_OFF   = RBOX_OFF  + (size_t)BATCH * TOPK * 16;      // f32 [16][1000][4]
constexpr size_t RCLS_OFF  = RBO_OFF   + (size_t)BATCH * TOPK * 16;      // f32 [16][1000]
constexpr size_t SUP_OFF   = RCLS_OFF  + (size_t)BATCH * TOPK * 4;       // u64 [16][1000][16]
constexpr size_t ORDER_OFF = SUP_OFF   + (size_t)BATCH * TOPK * 16 * 8;  // i32 [16][300]
constexpr size_t KC_OFF    = ORDER_OFF + (size_t)BATCH * MAXDET * 4;     // i32 [16]

// ---------------- zero scratch ----------------
__global__ void zero_kernel(uint32_t* p, int n) {
    int i = blockIdx.x * blockDim.x + threadIdx.x;
    if (i < n) p[i] = 0;
}

// ---------------- fused 1x1-conv + decode ----------------
// Tile: 64 positions x 256 outputs, 256 threads, 8x8 micro-tile per thread.
template<int C, int NN>
__global__ __launch_bounds__(256)
void decode_kernel(const float* __restrict__ x, const float* __restrict__ w,
                   const float* __restrict__ bias, float* __restrict__ pred,
                   float* __restrict__ scoreArr, int* __restrict__ clsArr,
                   int lvlOff, float stride,
                   float aw0, float ah0, float aw1, float ah1, float aw2, float ah2)
{
    constexpr int NPOS = NN * NN;
    __shared__ float lds[2048 + 256 * 36];   // xs[32][64] then ws[256][36]
    float* xs = lds;
    float* ws = lds + 2048;

    const int tid = threadIdx.x;
    const int b   = blockIdx.y;
    const int pos0 = blockIdx.x * 64;
    const int po = tid & 7;    // position group: p = po*8 + u
    const int og = tid >> 3;   // output group:   o = og*8 + v

    float acc[8][8];
#pragma unroll
    for (int u = 0; u < 8; u++)
#pragma unroll
        for (int v = 0; v < 8; v++) acc[u][v] = 0.f;

    const float* xb = x + (size_t)b * C * NPOS;

    for (int k0 = 0; k0 < C; k0 += 32) {
        // stage xs[kc][p]: 32x64 floats as float4
#pragma unroll
        for (int i = 0; i < 2; i++) {
            int li = tid + i * 256;          // float4 id 0..511
            int kc = li >> 4;
            int p4 = (li & 15) * 4;
            float4 v4 = make_float4(0.f, 0.f, 0.f, 0.f);
            if (pos0 + p4 < NPOS)
                v4 = *(const float4*)(xb + (size_t)(k0 + kc) * NPOS + pos0 + p4);
            *(float4*)&xs[kc * 64 + p4] = v4;
        }
        // stage ws[o][kc] (pad 36): 256x32 floats as float4
#pragma unroll
        for (int i = 0; i < 8; i++) {
            int li = tid + i * 256;          // 0..2047
            int o = li >> 3;
            int kc4 = (li & 7) * 4;
            int oo = o < 255 ? o : 254;      // o==255 dummy (never consumed)
            float4 v4 = *(const float4*)(w + (size_t)oo * C + k0 + kc4);
            *(float4*)&ws[o * 36 + kc4] = v4;
        }
        __syncthreads();
#pragma unroll
        for (int kg = 0; kg < 8; kg++) {
            const int kc0 = kg * 4;
            float xr[4][8];
#pragma unroll
            for (int q = 0; q < 4; q++) {
                *(float4*)&xr[q][0] = *(const float4*)&xs[(kc0 + q) * 64 + po * 8];
                *(float4*)&xr[q][4] = *(const float4*)&xs[(kc0 + q) * 64 + po * 8 + 4];
            }
#pragma unroll
            for (int v = 0; v < 8; v++) {
                float4 wv4 = *(const float4*)&ws[(og * 8 + v) * 36 + kc0];
                float wv[4] = {wv4.x, wv4.y, wv4.z, wv4.w};
#pragma unroll
                for (int q = 0; q < 4; q++)
#pragma unroll
                    for (int u = 0; u < 8; u++)
                        acc[u][v] = fmaf(xr[q][u], wv[q], acc[u][v]);
            }
        }
        __syncthreads();
    }

    float bv[8];
#pragma unroll
    for (int v = 0; v < 8; v++) {
        int o = og * 8 + v;
        bv[v] = (o < 255) ? bias[o] : 0.f;
    }

    const float aw[3] = {aw0, aw1, aw2};
    const float ah[3] = {ah0, ah1, ah2};
    float* staged = lds;   // reuse: [64][86]
    const int validP = (NPOS - pos0) < 64 ? (NPOS - pos0) : 64;

#pragma unroll
    for (int a = 0; a < 3; a++) {
        __syncthreads();
#pragma unroll
        for (int v = 0; v < 8; v++) {
            int o = og * 8 + v;
            int j = o - a * 85;
            if (o < 255 && j >= 0 && j < 85) {
#pragma unroll
                for (int u = 0; u < 8; u++) {
                    int p = po * 8 + u;
                    int pos = pos0 + p;
                    float y = acc[u][v] + bv[v];
                    float s = 1.f / (1.f + expf(-y));
                    float val;
                    if (j == 0) {
                        float gx = (float)(pos % NN);
                        val = (2.f * s + gx - 0.5f) * stride;
                    } else if (j == 1) {
                        float gy = (float)(pos / NN);
                        val = (2.f * s + gy - 0.5f) * stride;
                    } else if (j == 2) {
                        float t = 2.f * s; val = t * t * aw[a];
                    } else if (j == 3) {
                        float t = 2.f * s; val = t * t * ah[a];
                    } else {
                        val = s;
                    }
                    staged[p * 86 + j] = val;
                }
            }
        }
        __syncthreads();
        size_t base = ((size_t)b * NCAND + lvlOff + (size_t)a * NPOS + pos0) * 85;
        for (int q = tid; q < validP * 85; q += 256)
            pred[base + q] = staged[(q / 85) * 86 + (q % 85)];
        if (tid < validP) {
            int p = tid;
            float obj = staged[p * 86 + 4];
            float best = staged[p * 86 + 5];
            int bi = 0;
            for (int j = 6; j < 85; j++) {
                float vv = staged[p * 86 + j];
                if (vv > best) { best = vv; bi = j - 5; }
            }
            float sc = obj * best;
            int cand = lvlOff + a * NPOS + pos0 + p;
            scoreArr[b * NCAND + cand] = (sc > CONF) ? sc : 0.f;
            clsArr[b * NCAND + cand] = bi;
        }
    }
}

// ---------------- histogram of score float-bits (top 16 bits) ----------------
__global__ void hist_kernel(const float* __restrict__ score, uint32_t* __restrict__ hist) {
    int i = blockIdx.x * 256 + threadIdx.x;
    if (i >= BATCH * NCAND) return;
    float s = score[i];
    if (s > CONF) {
        int img = i / NCAND;
        uint32_t bits = __float_as_uint(s);
        atomicAdd(&hist[img * NBUCK + (bits >> 15)], 1u);
    }
}

// ---------------- find per-image bit-threshold for top-1000 ----------------
__global__ __launch_bounds__(256)
void thresh_kernel(const uint32_t* __restrict__ hist, uint32_t* __restrict__ thrbits) {
    int img = blockIdx.x, tid = threadIdx.x;
    __shared__ uint32_t part[256];
    __shared__ uint32_t hb[256];
    __shared__ int chunkSh;
    const uint32_t* h = hist + (size_t)img * NBUCK;
    uint32_t s = 0;
    for (int bb = tid * 256; bb < tid * 256 + 256; bb++) s += h[bb];
    part[tid] = s;
    __syncthreads();
    for (int off = 1; off < 256; off <<= 1) {           // suffix sums
        uint32_t v = part[tid] + ((tid + off < 256) ? part[tid + off] : 0);
        __syncthreads();
        part[tid] = v;
        __syncthreads();
    }
    uint32_t M = part[0];
    if (M == 0) { if (tid == 0) thrbits[img] = 0xFFFFFFFFu; return; }
    uint32_t target = M < TOPK ? M : TOPK;
    if (part[tid] >= target && (tid == 255 || part[tid + 1] < target)) chunkSh = tid;
    __syncthreads();
    int chunk = chunkSh;
    hb[tid] = h[chunk * 256 + tid];
    __syncthreads();
    if (tid == 0) {
        uint32_t running = (chunk < 255) ? part[chunk + 1] : 0;
        int bsel = 0;
        for (int bb = 255; bb >= 0; bb--) {
            running += hb[bb];
            if (running >= target) { bsel = bb; break; }
        }
        thrbits[img] = (uint32_t)(chunk * 256 + bsel) << 15;
    }
}

// ---------------- compact candidates above threshold ----------------
__global__ void compact_kernel(const float* __restrict__ score, const uint32_t* __restrict__ thrbits,
                               uint32_t* __restrict__ cnt, uint64_t* __restrict__ keys) {
    int i = blockIdx.x * 256 + threadIdx.x;
    if (i >= BATCH * NCAND) return;
    float s = score[i];
    if (s <= CONF) return;
    int img = i / NCAND;
    uint32_t bits = __float_as_uint(s);
    if (bits >= thrbits[img]) {
        uint32_t pos = atomicAdd(&cnt[img], 1u);
        if (pos < CAPK) {
            uint32_t idx = (uint32_t)(i - img * NCAND);
            keys[(size_t)img * CAPK + pos] = ((uint64_t)bits << 32) | (uint32_t)(~idx);
        }
    }
}

// ---------------- per-image bitonic sort + emit rank arrays ----------------
__global__ __launch_bounds__(1024)
void sort_kernel(const uint64_t* __restrict__ keys, const uint32_t* __restrict__ cnt,
                 const float* __restrict__ pred, const int* __restrict__ clsArr,
                 float* __restrict__ rs, float* __restrict__ rbox,
                 float* __restrict__ rbo, float* __restrict__ rcls) {
    int img = blockIdx.x, tid = threadIdx.x;
    __shared__ uint64_t sk[CAPK];
    uint32_t n = cnt[img];
    if (n > CAPK) n = CAPK;
    for (int i = tid; i < CAPK; i += 1024)
        sk[i] = (i < (int)n) ? keys[(size_t)img * CAPK + i] : 0ull;
    __syncthreads();
    for (int k = 2; k <= CAPK; k <<= 1)
        for (int j = k >> 1; j > 0; j >>= 1) {
            for (int i = tid; i < CAPK; i += 1024) {
                int l = i ^ j;
                if (l > i) {
                    uint64_t a = sk[i], b = sk[l];
                    bool descRegion = ((i & k) == 0);
                    bool sw = descRegion ? (a < b) : (a > b);
                    if (sw) { sk[i] = b; sk[l] = a; }
                }
            }
            __syncthreads();
        }
    for (int r = tid; r < TOPK; r += 1024) {
        float sc = 0.f; uint32_t idx = 0;
        if (r < (int)n) {
            uint64_t key = sk[r];
            sc = __uint_as_float((uint32_t)(key >> 32));
            idx = ~(uint32_t)key;
        }
        const float* pr = pred + ((size_t)img * NCAND + idx) * 85;
        float cx = pr[0], cy = pr[1], ww = pr[2], hh = pr[3];
        float x1 = cx - ww * 0.5f, y1 = cy - hh * 0.5f;
        float x2 = cx + ww * 0.5f, y2 = cy + hh * 0.5f;
        float c = (float)clsArr[(size_t)img * NCAND + idx];
        float off = c * MAXWH;
        size_t rb = ((size_t)img * TOPK + r) * 4;
        rbox[rb + 0] = x1; rbox[rb + 1] = y1; rbox[rb + 2] = x2; rbox[rb + 3] = y2;
        rbo[rb + 0] = x1 + off; rbo[rb + 1] = y1 + off;
        rbo[rb + 2] = x2 + off; rbo[rb + 3] = y2 + off;
        rs[(size_t)img * TOPK + r] = sc;
        rcls[(size_t)img * TOPK + r] = c;
    }
}

// ---------------- suppression bitmask: sup[img][i][w] bits j=w*64+l ----------------
__global__ __launch_bounds__(256)
void sup_kernel(const float* __restrict__ rbo, uint64_t* __restrict__ sup) {
    int img = blockIdx.y;
    int wid = threadIdx.x >> 6, lane = threadIdx.x & 63;
    int i = blockIdx.x * 4 + wid;
    if (i >= TOPK) return;
    const float* bi_ = rbo + ((size_t)img * TOPK + i) * 4;
    float ax1 = bi_[0], ay1 = bi_[1], ax2 = bi_[2], ay2 = bi_[3];
    float areaA = (ax2 - ax1) * (ay2 - ay1);
    for (int w = 0; w < 16; w++) {
        int j = w * 64 + lane;
        bool cond = false;
        if (j < TOPK && j > i) {
            const float* bj = rbo + ((size_t)img * TOPK + j) * 4;
            float bx1 = bj[0], by1 = bj[1], bx2 = bj[2], by2 = bj[3];
            float ltx = fmaxf(ax1, bx1), lty = fmaxf(ay1, by1);
            float rbx = fminf(ax2, bx2), rby = fminf(ay2, by2);
            float iw = fmaxf(rbx - ltx, 0.f), ih = fmaxf(rby - lty, 0.f);
            float inter = iw * ih;
            float areaB = (bx2 - bx1) * (by2 - by1);
            float iou = inter / (areaA + areaB - inter + 1e-7f);
            cond = iou > IOUT;
        }
        unsigned long long m = __ballot(cond);
        if (lane == w) sup[(((size_t)img * TOPK) + i) * 16 + w] = m;
    }
}

// ---------------- greedy NMS: one wave per image, iterate surviving bits ----------------
__global__ __launch_bounds__(64)
void greedy_kernel(const float* __restrict__ rs, const uint64_t* __restrict__ sup,
                   int* __restrict__ order, int* __restrict__ kcount) {
    int img = blockIdx.x, lane = threadIdx.x;
    __shared__ uint64_t keep[16];
    for (int w = 0; w < 16; w++) {
        int r = w * 64 + lane;
        bool k = (r < TOPK) && (rs[(size_t)img * TOPK + r] > CONF);
        unsigned long long m = __ballot(k);
        if (lane == w) keep[w] = m;
    }
    __syncthreads();
    const uint64_t* supim = sup + (size_t)img * TOPK * 16;
    int kept = 0, i = 0;
    while (i < TOPK && kept < MAXDET) {
        int w = i >> 6;
        uint64_t word = keep[w] & (~0ull << (i & 63));
        if (word == 0) { i = (w + 1) << 6; continue; }
        int bpos = __ffsll((unsigned long long)word) - 1;
        i = (w << 6) + bpos;
        if (lane == 0) order[img * MAXDET + kept] = i;
        kept++;
        uint64_t srow = (lane < 16) ? supim[(size_t)i * 16 + lane] : 0ull;
        if (lane < 16) keep[lane] &= ~srow;
        __syncthreads();
        i++;
    }
    if (lane == 0) kcount[img] = kept;
}

// ---------------- emit dets ----------------
__global__ __launch_bounds__(256)
void final_kernel(const int* __restrict__ order, const int* __restrict__ kcount,
                  const float* __restrict__ rbox, const float* __restrict__ rs,
                  const float* __restrict__ rcls, float* __restrict__ dets) {
    int img = blockIdx.x, tid = threadIdx.x;
    float* d = dets + (size_t)img * MAXDET * 6;
    for (int q = tid; q < MAXDET * 6; q += 256) d[q] = 0.f;
    __syncthreads();
    int kc = kcount[img];
    for (int r = tid; r < kc; r += 256) {
        int i = order[img * MAXDET + r];
        const float* bx = rbox + ((size_t)img * TOPK + i) * 4;
        d[r * 6 + 0] = bx[0]; d[r * 6 + 1] = bx[1];
        d[r * 6 + 2] = bx[2]; d[r * 6 + 3] = bx[3];
        d[r * 6 + 4] = rs[(size_t)img * TOPK + i];
        d[r * 6 + 5] = rcls[(size_t)img * TOPK + i];
    }
}

extern "C" void kernel_launch(void* const* d_in, const int* in_sizes, int n_in,
                              void* d_out, int out_size, void* d_ws, size_t ws_size,
                              hipStream_t stream) {
    const float* x0 = (const float*)d_in[0];
    const float* x1 = (const float*)d_in[1];
    const float* x2 = (const float*)d_in[2];
    const float* w0 = (const float*)d_in[3];
    const float* b0 = (const float*)d_in[4];
    const float* w1 = (const float*)d_in[5];
    const float* b1 = (const float*)d_in[6];
    const float* w2 = (const float*)d_in[7];
    const float* b2 = (const float*)d_in[8];

    float* dets = (float*)d_out;
    float* pred = dets + (size_t)BATCH * MAXDET * 6;

    char* ws = (char*)d_ws;
    float*    scoreArr = (float*)   (ws + SCORE_OFF);
    int*      clsArr   = (int*)     (ws + CLS_OFF);
    uint32_t* hist     = (uint32_t*)(ws + HIST_OFF);
    uint32_t* thrb     = (uint32_t*)(ws + THR_OFF);
    uint32_t* cnt      = (uint32_t*)(ws + CNT_OFF);
    uint64_t* keys     = (uint64_t*)(ws + KEYS_OFF);
    float*    rs       = (float*)   (ws + RS_OFF);
    float*    rbox     = (float*)   (ws + RBOX_OFF);
    float*    rbo      = (float*)   (ws + RBO_OFF);
    float*    rcls     = (float*)   (ws + RCLS_OFF);
    uint64_t* sup      = (uint64_t*)(ws + SUP_OFF);
    int*      order    = (int*)     (ws + ORDER_OFF);
    int*      kcount   = (int*)     (ws + KC_OFF);

    int zn = (int)((KEYS_OFF - HIST_OFF) / 4);
    zero_kernel<<<(zn + 255) / 256, 256, 0, stream>>>((uint32_t*)(ws + HIST_OFF), zn);

    decode_kernel<128, 80><<<dim3(100, BATCH), 256, 0, stream>>>(
        x0, w0, b0, pred, scoreArr, clsArr, 0, 8.f,
        80.f, 104.f, 128.f, 240.f, 264.f, 184.f);
    decode_kernel<256, 40><<<dim3(25, BATCH), 256, 0, stream>>>(
        x1, w1, b1, pred, scoreArr, clsArr, 19200, 16.f,
        480.f, 976.f, 992.f, 720.f, 944.f, 1904.f);
    decode_kernel<512, 20><<<dim3(7, BATCH), 256, 0, stream>>>(
        x2, w2, b2, pred, scoreArr, clsArr, 24000, 32.f,
        3712.f, 2880.f, 4992.f, 6336.f, 11936.f, 10432.f);

    int tot = BATCH * NCAND;
    hist_kernel<<<(tot + 255) / 256, 256, 0, stream>>>(scoreArr, hist);
    thresh_kernel<<<BATCH, 256, 0, stream>>>(hist, thrb);
    compact_kernel<<<(tot + 255) / 256, 256, 0, stream>>>(scoreArr, thrb, cnt, keys);
    sort_kernel<<<BATCH, 1024, 0, stream>>>(keys, cnt, pred, clsArr, rs, rbox, rbo, rcls);
    sup_kernel<<<dim3(250, BATCH), 256, 0, stream>>>(rbo, sup);
    greedy_kernel<<<BATCH, 64, 0, stream>>>(rs, sup, order, kcount);
    final_kernel<<<BATCH, 256, 0, stream>>>(order, kcount, rbox, rs, rcls, dets);
}

// Round 2
// 483.787 us; speedup vs baseline: 1.5430x; 1.5430x over previous
//
#include <hip/hip_runtime.h>
#include <cstdint>

#define BATCH   16
#define NCLS    80
#define NOUT    85      // 5 + NCLS
#define NANC    3
#define NCAND   25200   // 3*(6400+1600+400)
#define CONF    0.25f
#define IOUT    0.45f
#define TOPK    1000
#define MAXDET  300
#define MAXWH   4096.0f
#define CAPK    2048
#define NBH     520     // hist buckets: (bits>>15) - 0x7D00, scores in (0.25, 1]

// ---------------- workspace layout (bytes) ----------------
constexpr size_t SCORE_OFF = 0;                                          // f32 [16][25200]
constexpr size_t CLS_OFF   = SCORE_OFF + (size_t)BATCH * NCAND * 4;      // i32 [16][25200]
constexpr size_t THR_OFF   = CLS_OFF   + (size_t)BATCH * NCAND * 4;      // u32 [16] (+pad)
constexpr size_t CNT_OFF   = THR_OFF   + 256;                            // u32 [16] (+pad)
constexpr size_t KEYS_OFF  = CNT_OFF   + 256;                            // u64 [16][2048]
constexpr size_t RS_OFF    = KEYS_OFF  + (size_t)BATCH * CAPK * 8;       // f32 [16][1000]
constexpr size_t RBOX_OFF  = RS_OFF    + (size_t)BATCH * TOPK * 4;       // f32 [16][1000][4]
constexpr size_t RBO_OFF   = RBOX_OFF  + (size_t)BATCH * TOPK * 16;      // f32 [16][1000][4]
constexpr size_t RCLS_OFF  = RBO_OFF   + (size_t)BATCH * TOPK * 16;      // f32 [16][1000]
constexpr size_t SUP_OFF   = RCLS_OFF  + (size_t)BATCH * TOPK * 4;       // u64 [16][1000][16]
constexpr size_t ORDER_OFF = SUP_OFF   + (size_t)BATCH * TOPK * 16 * 8;  // i32 [16][300]
constexpr size_t KC_OFF    = ORDER_OFF + (size_t)BATCH * MAXDET * 4;     // i32 [16]

// ---------------- fused 1x1-conv + decode ----------------
// Tile: 64 positions x 256 outputs, 256 threads, 8x8 micro-tile per thread.
template<int C, int NN>
__global__ __launch_bounds__(256)
void decode_kernel(const float* __restrict__ x, const float* __restrict__ w,
                   const float* __restrict__ bias, float* __restrict__ pred,
                   float* __restrict__ scoreArr, int* __restrict__ clsArr,
                   int lvlOff, float stride,
                   float aw0, float ah0, float aw1, float ah1, float aw2, float ah2)
{
    constexpr int NPOS = NN * NN;
    __shared__ float lds[2048 + 256 * 36];   // xs[32][64] then ws[256][36]
    float* xs = lds;
    float* ws = lds + 2048;

    const int tid = threadIdx.x;
    const int b   = blockIdx.y;
    const int pos0 = blockIdx.x * 64;
    const int po = tid & 7;    // position group: p = po*8 + u
    const int og = tid >> 3;   // output group:   o = og*8 + v

    float acc[8][8];
#pragma unroll
    for (int u = 0; u < 8; u++)
#pragma unroll
        for (int v = 0; v < 8; v++) acc[u][v] = 0.f;

    const float* xb = x + (size_t)b * C * NPOS;

    for (int k0 = 0; k0 < C; k0 += 32) {
        // stage xs[kc][p]: 32x64 floats as float4
#pragma unroll
        for (int i = 0; i < 2; i++) {
            int li = tid + i * 256;          // float4 id 0..511
            int kc = li >> 4;
            int p4 = (li & 15) * 4;
            float4 v4 = make_float4(0.f, 0.f, 0.f, 0.f);
            if (pos0 + p4 < NPOS)
                v4 = *(const float4*)(xb + (size_t)(k0 + kc) * NPOS + pos0 + p4);
            *(float4*)&xs[kc * 64 + p4] = v4;
        }
        // stage ws[o][kc] (pad 36): 256x32 floats as float4
#pragma unroll
        for (int i = 0; i < 8; i++) {
            int li = tid + i * 256;          // 0..2047
            int o = li >> 3;
            int kc4 = (li & 7) * 4;
            int oo = o < 255 ? o : 254;      // o==255 dummy (never consumed)
            float4 v4 = *(const float4*)(w + (size_t)oo * C + k0 + kc4);
            *(float4*)&ws[o * 36 + kc4] = v4;
        }
        __syncthreads();
#pragma unroll
        for (int kg = 0; kg < 8; kg++) {
            const int kc0 = kg * 4;
            float xr[4][8];
#pragma unroll
            for (int q = 0; q < 4; q++) {
                *(float4*)&xr[q][0] = *(const float4*)&xs[(kc0 + q) * 64 + po * 8];
                *(float4*)&xr[q][4] = *(const float4*)&xs[(kc0 + q) * 64 + po * 8 + 4];
            }
#pragma unroll
            for (int v = 0; v < 8; v++) {
                float4 wv4 = *(const float4*)&ws[(og * 8 + v) * 36 + kc0];
                float wv[4] = {wv4.x, wv4.y, wv4.z, wv4.w};
#pragma unroll
                for (int q = 0; q < 4; q++)
#pragma unroll
                    for (int u = 0; u < 8; u++)
                        acc[u][v] = fmaf(xr[q][u], wv[q], acc[u][v]);
            }
        }
        __syncthreads();
    }

    float bv[8];
#pragma unroll
    for (int v = 0; v < 8; v++) {
        int o = og * 8 + v;
        bv[v] = (o < 255) ? bias[o] : 0.f;
    }

    const float aw[3] = {aw0, aw1, aw2};
    const float ah[3] = {ah0, ah1, ah2};
    float* staged = lds;   // reuse: [64][86]
    const int validP = (NPOS - pos0) < 64 ? (NPOS - pos0) : 64;

#pragma unroll
    for (int a = 0; a < 3; a++) {
        __syncthreads();
#pragma unroll
        for (int v = 0; v < 8; v++) {
            int o = og * 8 + v;
            int j = o - a * 85;
            if (o < 255 && j >= 0 && j < 85) {
#pragma unroll
                for (int u = 0; u < 8; u++) {
                    int p = po * 8 + u;
                    int pos = pos0 + p;
                    float y = acc[u][v] + bv[v];
                    float s = 1.f / (1.f + expf(-y));
                    float val;
                    if (j == 0) {
                        float gx = (float)(pos % NN);
                        val = (2.f * s + gx - 0.5f) * stride;
                    } else if (j == 1) {
                        float gy = (float)(pos / NN);
                        val = (2.f * s + gy - 0.5f) * stride;
                    } else if (j == 2) {
                        float t = 2.f * s; val = t * t * aw[a];
                    } else if (j == 3) {
                        float t = 2.f * s; val = t * t * ah[a];
                    } else {
                        val = s;
                    }
                    staged[p * 86 + j] = val;
                }
            }
        }
        __syncthreads();
        size_t base = ((size_t)b * NCAND + lvlOff + (size_t)a * NPOS + pos0) * 85;
        for (int q = tid; q < validP * 85; q += 256)
            pred[base + q] = staged[(q / 85) * 86 + (q % 85)];
        if (tid < validP) {
            int p = tid;
            float obj = staged[p * 86 + 4];
            float best = staged[p * 86 + 5];
            int bi = 0;
            for (int j = 6; j < 85; j++) {
                float vv = staged[p * 86 + j];
                if (vv > best) { best = vv; bi = j - 5; }
            }
            float sc = obj * best;
            int cand = lvlOff + a * NPOS + pos0 + p;
            scoreArr[b * NCAND + cand] = (sc > CONF) ? sc : 0.f;
            clsArr[b * NCAND + cand] = bi;
        }
    }
}

// ---------------- fused LDS histogram + top-1000 bit-threshold (one block/image) ----
__global__ __launch_bounds__(1024)
void topk_thresh_kernel(const float* __restrict__ score, uint32_t* __restrict__ thrbits,
                        uint32_t* __restrict__ cnt) {
    int img = blockIdx.x, tid = threadIdx.x;
    __shared__ uint32_t h[NBH];
    __shared__ uint32_t sfx[1024 + 1];
    __shared__ int bucketSh;
    for (int i = tid; i < NBH; i += 1024) h[i] = 0;
    __syncthreads();
    const float* s = score + (size_t)img * NCAND;
    for (int i = tid; i < NCAND; i += 1024) {
        float v = s[i];
        if (v > CONF) {
            int bk = (int)((__float_as_uint(v) >> 15) - 0x7D00u);
            bk = bk < 0 ? 0 : (bk >= NBH ? NBH - 1 : bk);
            atomicAdd(&h[bk], 1u);
        }
    }
    __syncthreads();
    sfx[tid] = (tid < NBH) ? h[tid] : 0u;
    if (tid == 0) sfx[1024] = 0u;
    __syncthreads();
    for (int off = 1; off < 1024; off <<= 1) {
        uint32_t v = sfx[tid] + ((tid + off < 1024) ? sfx[tid + off] : 0u);
        __syncthreads();
        sfx[tid] = v;
        __syncthreads();
    }
    uint32_t M = sfx[0];
    uint32_t target = M < TOPK ? M : TOPK;
    if (M > 0 && tid < NBH && sfx[tid] >= target && sfx[tid + 1] < target)
        bucketSh = tid;
    __syncthreads();
    if (tid == 0) {
        thrbits[img] = (M == 0) ? 0xFFFFFFFFu
                                : ((uint32_t)(bucketSh + 0x7D00) << 15);
        cnt[img] = 0u;
    }
}

// ---------------- compact candidates above threshold (wave-aggregated atomics) ----
__global__ __launch_bounds__(256)
void compact_kernel(const float* __restrict__ score, const uint32_t* __restrict__ thrbits,
                    uint32_t* __restrict__ cnt, uint64_t* __restrict__ keys) {
    int img = blockIdx.y;
    int i = blockIdx.x * 256 + threadIdx.x;
    int lane = threadIdx.x & 63;
    uint32_t thr = thrbits[img];
    bool pass = false;
    uint32_t bits = 0;
    if (i < NCAND) {
        float s = score[(size_t)img * NCAND + i];
        bits = __float_as_uint(s);
        pass = (s > CONF) && (bits >= thr);
    }
    unsigned long long m = __ballot(pass);
    if (m) {
        int leader = __ffsll(m) - 1;
        uint32_t base = 0;
        if (lane == leader) base = atomicAdd(&cnt[img], (uint32_t)__popcll(m));
        base = __shfl(base, leader);
        if (pass) {
            uint32_t pos = base + (uint32_t)__popcll(m & ((1ull << lane) - 1ull));
            if (pos < CAPK)
                keys[(size_t)img * CAPK + pos] =
                    ((uint64_t)bits << 32) | (uint32_t)(~(uint32_t)i);
        }
    }
}

// ---------------- per-image bitonic sort + emit rank arrays ----------------
__global__ __launch_bounds__(1024)
void sort_kernel(const uint64_t* __restrict__ keys, const uint32_t* __restrict__ cnt,
                 const float* __restrict__ pred, const int* __restrict__ clsArr,
                 float* __restrict__ rs, float* __restrict__ rbox,
                 float* __restrict__ rbo, float* __restrict__ rcls) {
    int img = blockIdx.x, tid = threadIdx.x;
    __shared__ uint64_t sk[CAPK];
    uint32_t n = cnt[img];
    if (n > CAPK) n = CAPK;
    for (int i = tid; i < CAPK; i += 1024)
        sk[i] = (i < (int)n) ? keys[(size_t)img * CAPK + i] : 0ull;
    __syncthreads();
    for (int k = 2; k <= CAPK; k <<= 1)
        for (int j = k >> 1; j > 0; j >>= 1) {
            for (int i = tid; i < CAPK; i += 1024) {
                int l = i ^ j;
                if (l > i) {
                    uint64_t a = sk[i], b = sk[l];
                    bool descRegion = ((i & k) == 0);
                    bool sw = descRegion ? (a < b) : (a > b);
                    if (sw) { sk[i] = b; sk[l] = a; }
                }
            }
            __syncthreads();
        }
    for (int r = tid; r < TOPK; r += 1024) {
        float sc = 0.f; uint32_t idx = 0;
        if (r < (int)n) {
            uint64_t key = sk[r];
            sc = __uint_as_float((uint32_t)(key >> 32));
            idx = ~(uint32_t)key;
        }
        const float* pr = pred + ((size_t)img * NCAND + idx) * 85;
        float cx = pr[0], cy = pr[1], ww = pr[2], hh = pr[3];
        float x1 = cx - ww * 0.5f, y1 = cy - hh * 0.5f;
        float x2 = cx + ww * 0.5f, y2 = cy + hh * 0.5f;
        float c = (float)clsArr[(size_t)img * NCAND + idx];
        float off = c * MAXWH;
        size_t rb = ((size_t)img * TOPK + r) * 4;
        rbox[rb + 0] = x1; rbox[rb + 1] = y1; rbox[rb + 2] = x2; rbox[rb + 3] = y2;
        rbo[rb + 0] = x1 + off; rbo[rb + 1] = y1 + off;
        rbo[rb + 2] = x2 + off; rbo[rb + 3] = y2 + off;
        rs[(size_t)img * TOPK + r] = sc;
        rcls[(size_t)img * TOPK + r] = c;
    }
}

// ---------------- suppression bitmask: sup[img][i][w] bits j=w*64+l ----------------
__global__ __launch_bounds__(256)
void sup_kernel(const float* __restrict__ rbo, uint64_t* __restrict__ sup) {
    int img = blockIdx.y;
    int wid = threadIdx.x >> 6, lane = threadIdx.x & 63;
    int i = blockIdx.x * 4 + wid;
    if (i >= TOPK) return;
    const float* bi_ = rbo + ((size_t)img * TOPK + i) * 4;
    float ax1 = bi_[0], ay1 = bi_[1], ax2 = bi_[2], ay2 = bi_[3];
    float areaA = (ax2 - ax1) * (ay2 - ay1);
    for (int w = 0; w < 16; w++) {
        int j = w * 64 + lane;
        bool cond = false;
        if (j < TOPK && j > i) {
            const float* bj = rbo + ((size_t)img * TOPK + j) * 4;
            float bx1 = bj[0], by1 = bj[1], bx2 = bj[2], by2 = bj[3];
            float ltx = fmaxf(ax1, bx1), lty = fmaxf(ay1, by1);
            float rbx = fminf(ax2, bx2), rby = fminf(ay2, by2);
            float iw = fmaxf(rbx - ltx, 0.f), ih = fmaxf(rby - lty, 0.f);
            float inter = iw * ih;
            float areaB = (bx2 - bx1) * (by2 - by1);
            float iou = inter / (areaA + areaB - inter + 1e-7f);
            cond = iou > IOUT;
        }
        unsigned long long m = __ballot(cond);
        if (lane == w) sup[(((size_t)img * TOPK) + i) * 16 + w] = m;
    }
}

// ---------------- blocked greedy NMS: one wave/image, 64x64 diagonal in-register --
__global__ __launch_bounds__(64)
void greedy_kernel(const float* __restrict__ rs, const uint64_t* __restrict__ sup,
                   int* __restrict__ order, int* __restrict__ kcount) {
    int img = blockIdx.x, lane = threadIdx.x;
    __shared__ uint32_t keep32[32];
    __shared__ uint16_t accList[64];
    // init keep bits from rs > CONF
    for (int w = 0; w < 16; w++) {
        int r = w * 64 + lane;
        bool k = (r < TOPK) && (rs[(size_t)img * TOPK + r] > CONF);
        unsigned long long m = __ballot(k);
        if (lane == 0) {
            keep32[2 * w]     = (uint32_t)m;
            keep32[2 * w + 1] = (uint32_t)(m >> 32);
        }
    }
    __syncthreads();
    const uint64_t* supim = sup + (size_t)img * TOPK * 16;
    int kept = 0;
    for (int wb = 0; wb < 16 && kept < MAXDET; wb++) {
        uint64_t word = ((uint64_t)keep32[2 * wb + 1] << 32) | keep32[2 * wb];
        if (!word) continue;
        // each lane holds the diagonal word of its row
        uint64_t diag = 0;
        int myIdx = wb * 64 + lane;
        if (myIdx < TOPK) diag = supim[(size_t)myIdx * 16 + wb];
        // serial greedy resolve within the 64x64 diagonal block (uniform regs)
        uint64_t cur = word, acc = 0;
        for (int b = 0; b < 64; b++) {
            uint64_t row = __shfl(diag, b);
            if ((cur >> b) & 1ull) { acc |= 1ull << b; cur &= ~row; }
            if (!cur) break;
        }
        int nb = __popcll(acc);
        // truncate to MAXDET
        if (kept + nb > MAXDET) {
            int t = MAXDET - kept;
            bool mine = (acc >> lane) & 1ull;
            int rank = __popcll(acc & ((1ull << lane) - 1ull));
            acc = __ballot(mine && rank < t);
            nb = t;
        }
        // emit accepted indices (ascending = greedy order)
        {
            bool mine = (acc >> lane) & 1ull;
            int rank = __popcll(acc & ((1ull << lane) - 1ull));
            if (mine) {
                order[img * MAXDET + kept + rank] = wb * 64 + lane;
                accList[rank] = (uint16_t)(wb * 64 + lane);
            }
        }
        kept += nb;
        if (kept >= MAXDET) break;
        __syncthreads();
        // apply accepted rows' suppression to later words (parallel, independent loads)
        int nw = 15 - wb;
        if (nw > 0 && nb > 0) {
            int P = nb * nw;
            for (int p = lane; p < P; p += 64) {
                int bi = p / nw, wq = wb + 1 + p % nw;
                int srcIdx = accList[bi];
                uint64_t row = supim[(size_t)srcIdx * 16 + wq];
                uint32_t lo = (uint32_t)row, hi = (uint32_t)(row >> 32);
                if (lo) atomicAnd(&keep32[2 * wq], ~lo);
                if (hi) atomicAnd(&keep32[2 * wq + 1], ~hi);
            }
        }
        __syncthreads();
    }
    if (lane == 0) kcount[img] = kept;
}

// ---------------- emit dets ----------------
__global__ __launch_bounds__(256)
void final_kernel(const int* __restrict__ order, const int* __restrict__ kcount,
                  const float* __restrict__ rbox, const float* __restrict__ rs,
                  const float* __restrict__ rcls, float* __restrict__ dets) {
    int img = blockIdx.x, tid = threadIdx.x;
    float* d = dets + (size_t)img * MAXDET * 6;
    for (int q = tid; q < MAXDET * 6; q += 256) d[q] = 0.f;
    __syncthreads();
    int kc = kcount[img];
    for (int r = tid; r < kc; r += 256) {
        int i = order[img * MAXDET + r];
        const float* bx = rbox + ((size_t)img * TOPK + i) * 4;
        d[r * 6 + 0] = bx[0]; d[r * 6 + 1] = bx[1];
        d[r * 6 + 2] = bx[2]; d[r * 6 + 3] = bx[3];
        d[r * 6 + 4] = rs[(size_t)img * TOPK + i];
        d[r * 6 + 5] = rcls[(size_t)img * TOPK + i];
    }
}

extern "C" void kernel_launch(void* const* d_in, const int* in_sizes, int n_in,
                              void* d_out, int out_size, void* d_ws, size_t ws_size,
                              hipStream_t stream) {
    const float* x0 = (const float*)d_in[0];
    const float* x1 = (const float*)d_in[1];
    const float* x2 = (const float*)d_in[2];
    const float* w0 = (const float*)d_in[3];
    const float* b0 = (const float*)d_in[4];
    const float* w1 = (const float*)d_in[5];
    const float* b1 = (const float*)d_in[6];
    const float* w2 = (const float*)d_in[7];
    const float* b2 = (const float*)d_in[8];

    float* dets = (float*)d_out;
    float* pred = dets + (size_t)BATCH * MAXDET * 6;

    char* ws = (char*)d_ws;
    float*    scoreArr = (float*)   (ws + SCORE_OFF);
    int*      clsArr   = (int*)     (ws + CLS_OFF);
    uint32_t* thrb     = (uint32_t*)(ws + THR_OFF);
    uint32_t* cnt      = (uint32_t*)(ws + CNT_OFF);
    uint64_t* keys     = (uint64_t*)(ws + KEYS_OFF);
    float*    rs       = (float*)   (ws + RS_OFF);
    float*    rbox     = (float*)   (ws + RBOX_OFF);
    float*    rbo      = (float*)   (ws + RBO_OFF);
    float*    rcls     = (float*)   (ws + RCLS_OFF);
    uint64_t* sup      = (uint64_t*)(ws + SUP_OFF);
    int*      order    = (int*)     (ws + ORDER_OFF);
    int*      kcount   = (int*)     (ws + KC_OFF);

    decode_kernel<128, 80><<<dim3(100, BATCH), 256, 0, stream>>>(
        x0, w0, b0, pred, scoreArr, clsArr, 0, 8.f,
        80.f, 104.f, 128.f, 240.f, 264.f, 184.f);
    decode_kernel<256, 40><<<dim3(25, BATCH), 256, 0, stream>>>(
        x1, w1, b1, pred, scoreArr, clsArr, 19200, 16.f,
        480.f, 976.f, 992.f, 720.f, 944.f, 1904.f);
    decode_kernel<512, 20><<<dim3(7, BATCH), 256, 0, stream>>>(
        x2, w2, b2, pred, scoreArr, clsArr, 24000, 32.f,
        3712.f, 2880.f, 4992.f, 6336.f, 11936.f, 10432.f);

    topk_thresh_kernel<<<BATCH, 1024, 0, stream>>>(scoreArr, thrb, cnt);
    compact_kernel<<<dim3((NCAND + 255) / 256, BATCH), 256, 0, stream>>>(scoreArr, thrb, cnt, keys);
    sort_kernel<<<BATCH, 1024, 0, stream>>>(keys, cnt, pred, clsArr, rs, rbox, rbo, rcls);
    sup_kernel<<<dim3(250, BATCH), 256, 0, stream>>>(rbo, sup);
    greedy_kernel<<<BATCH, 64, 0, stream>>>(rs, sup, order, kcount);
    final_kernel<<<BATCH, 256, 0, stream>>>(order, kcount, rbox, rs, rcls, dets);
}